// Round 1
// baseline (1875.144 us; speedup 1.0000x reference)
//
#include <hip/hip_runtime.h>
#include <cstdint>
#include <cstddef>

#define HEADS 4
#define HID 16
#define HD 64          // HEADS*HID
#define NCLS 10
#define NGRAPH 128
#define NEG_SLOPE 0.2f
#define SM_EPS 1e-16f

static inline size_t alignup(size_t x) { return (x + 255) & ~size_t(255); }

// Monotonic float<->uint mapping so atomicMax(unsigned) implements float max.
__device__ __forceinline__ unsigned flipf(float f) {
    unsigned u = __float_as_uint(f);
    return (u & 0x80000000u) ? ~u : (u | 0x80000000u);
}
__device__ __forceinline__ float unflipf(unsigned v) {
    unsigned u = (v & 0x80000000u) ? (v ^ 0x80000000u) : ~v;
    return __uint_as_float(u);
}

// h = in @ W  : [N,K] @ [K,64] -> [N,64]
__global__ void gemm_kernel(const float* __restrict__ in, const float* __restrict__ W,
                            float* __restrict__ out, int N, int K) {
    int idx = blockIdx.x * blockDim.x + threadIdx.x;
    if (idx >= N * HD) return;
    int node = idx >> 6, col = idx & 63;
    const float* xr = in + (size_t)node * K;
    float acc = 0.f;
    for (int k = 0; k < K; k++) acc += xr[k] * W[k * HD + col];
    out[idx] = acc;
}

// a_src[n,h] = sum_d h[n,h,d]*as[h,d] ; same for a_dst
__global__ void attn_coef_kernel(const float* __restrict__ h, const float* __restrict__ as_,
                                 const float* __restrict__ ad_, float* __restrict__ asrc,
                                 float* __restrict__ adst, int N) {
    int idx = blockIdx.x * blockDim.x + threadIdx.x;  // node*HEADS + head
    if (idx >= N * HEADS) return;
    int head = idx & 3;
    const float* hr = h + (size_t)(idx >> 2) * HD + head * HID;
    float s = 0.f, d = 0.f;
    for (int k = 0; k < HID; k++) {
        s += hr[k] * as_[head * HID + k];
        d += hr[k] * ad_[head * HID + k];
    }
    asrc[idx] = s;
    adst[idx] = d;
}

// logits + segment max (atomicMax on flipped uint)
__global__ void edge_logit_kernel(const int* __restrict__ srcA, const int* __restrict__ dstA,
                                  int E, int Etot, const float* __restrict__ asrc,
                                  const float* __restrict__ adst, float* __restrict__ elog,
                                  unsigned* __restrict__ mu) {
    int e = blockIdx.x * blockDim.x + threadIdx.x;
    if (e >= Etot) return;
    int s = (e < E) ? srcA[e] : (e - E);
    int d = (e < E) ? dstA[e] : (e - E);
#pragma unroll
    for (int h = 0; h < HEADS; h++) {
        float l = asrc[s * HEADS + h] + adst[d * HEADS + h];
        l = (l > 0.f) ? l : NEG_SLOPE * l;
        elog[(size_t)e * HEADS + h] = l;
        atomicMax(&mu[d * HEADS + h], flipf(l));
    }
}

// e = exp(logit - m[dst]) ; segment sum via atomicAdd
__global__ void edge_exp_kernel(const int* __restrict__ srcA, const int* __restrict__ dstA,
                                int E, int Etot, const unsigned* __restrict__ mu,
                                float* __restrict__ elog, float* __restrict__ ssum) {
    int e = blockIdx.x * blockDim.x + threadIdx.x;
    if (e >= Etot) return;
    int d = (e < E) ? dstA[e] : (e - E);
#pragma unroll
    for (int h = 0; h < HEADS; h++) {
        float m = unflipf(mu[d * HEADS + h]);
        float ex = expf(elog[(size_t)e * HEADS + h] - m);
        elog[(size_t)e * HEADS + h] = ex;
        atomicAdd(&ssum[d * HEADS + h], ex);
    }
}

// acc[dst, :] += h[src, :] * alpha  (thread per (edge, col))
__global__ void edge_aggr_kernel(const int* __restrict__ srcA, const int* __restrict__ dstA,
                                 int E, int Etot, const float* __restrict__ elog,
                                 const float* __restrict__ ssum, const float* __restrict__ hproj,
                                 float* __restrict__ acc) {
    long long t = (long long)blockIdx.x * blockDim.x + threadIdx.x;
    int e = (int)(t >> 6);
    if (e >= Etot) return;
    int col = (int)(t & 63), head = col >> 4;
    int s = (e < E) ? srcA[e] : (e - E);
    int d = (e < E) ? dstA[e] : (e - E);
    float alpha = elog[(size_t)e * HEADS + head] / (ssum[d * HEADS + head] + SM_EPS);
    atomicAdd(&acc[(size_t)d * HD + col], hproj[(size_t)s * HD + col] * alpha);
}

// out = silu(acc + b)
__global__ void bias_silu_kernel(const float* __restrict__ acc, const float* __restrict__ b,
                                 float* __restrict__ out, int N) {
    int idx = blockIdx.x * blockDim.x + threadIdx.x;
    if (idx >= N * HD) return;
    float v = acc[idx] + b[idx & 63];
    out[idx] = v / (1.f + expf(-v));
}

// pooled[batch[n], :] += h[n, :]
__global__ void pool_kernel(const float* __restrict__ h, const int* __restrict__ batch,
                            float* __restrict__ pooled, int N) {
    int idx = blockIdx.x * blockDim.x + threadIdx.x;
    if (idx >= N * HD) return;
    int node = idx >> 6;
    atomicAdd(&pooled[(size_t)batch[node] * HD + (idx & 63)], h[idx]);
}

// logits = relu(pooled @ Wr + br); out = log_softmax(logits)
__global__ void head_kernel(const float* __restrict__ pooled, const float* __restrict__ Wr,
                            const float* __restrict__ br, float* __restrict__ out) {
    int g = threadIdx.x;
    if (g >= NGRAPH) return;
    float l[NCLS];
    float mx = -1e30f;
#pragma unroll
    for (int c = 0; c < NCLS; c++) {
        float a = br[c];
        for (int k = 0; k < HD; k++) a += pooled[(size_t)g * HD + k] * Wr[k * NCLS + c];
        a = (a > 0.f) ? a : 0.f;
        l[c] = a;
        mx = fmaxf(mx, a);
    }
    float se = 0.f;
#pragma unroll
    for (int c = 0; c < NCLS; c++) se += expf(l[c] - mx);
    float lse = logf(se);
#pragma unroll
    for (int c = 0; c < NCLS; c++) out[(size_t)g * NCLS + c] = l[c] - mx - lse;
}

extern "C" void kernel_launch(void* const* d_in, const int* in_sizes, int n_in,
                              void* d_out, int out_size, void* d_ws, size_t ws_size,
                              hipStream_t stream) {
    const float* x = (const float*)d_in[0];
    const int* ei = (const int*)d_in[1];
    const int* batch = (const int*)d_in[2];
    const float* W[3]  = {(const float*)d_in[3], (const float*)d_in[7],  (const float*)d_in[11]};
    const float* bb[3] = {(const float*)d_in[4], (const float*)d_in[8],  (const float*)d_in[12]};
    const float* as_[3] = {(const float*)d_in[5], (const float*)d_in[9], (const float*)d_in[13]};
    const float* ad_[3] = {(const float*)d_in[6], (const float*)d_in[10], (const float*)d_in[14]};
    const float* Wr = (const float*)d_in[15];
    const float* br = (const float*)d_in[16];

    const int N = in_sizes[2];          // 50000
    const int E = in_sizes[1] / 2;      // 800000
    const int Etot = E + N;             // + self loops
    const int F0 = in_sizes[0] / N;     // 128

    char* p = (char*)d_ws;
    float* hproj = (float*)p; p += alignup((size_t)N * HD * 4);
    float* acc   = (float*)p; p += alignup((size_t)N * HD * 4);
    float* hbuf  = (float*)p; p += alignup((size_t)N * HD * 4);
    float* asrc  = (float*)p; p += alignup((size_t)N * HEADS * 4);
    float* adst  = (float*)p; p += alignup((size_t)N * HEADS * 4);
    unsigned* mu = (unsigned*)p; p += alignup((size_t)N * HEADS * 4);
    float* ssum  = (float*)p; p += alignup((size_t)N * HEADS * 4);
    float* elog  = (float*)p; p += alignup((size_t)Etot * HEADS * 4);
    float* pooled = (float*)p; p += alignup((size_t)NGRAPH * HD * 4);

    const int* srcA = ei;
    const int* dstA = ei + E;

    for (int layer = 0; layer < 3; layer++) {
        const float* in = (layer == 0) ? x : hbuf;
        int K = (layer == 0) ? F0 : HD;

        hipMemsetAsync(acc, 0, (size_t)N * HD * 4, stream);
        hipMemsetAsync(mu, 0, (size_t)N * HEADS * 4, stream);   // flip-space -inf
        hipMemsetAsync(ssum, 0, (size_t)N * HEADS * 4, stream);

        int tot = N * HD;
        gemm_kernel<<<(tot + 255) / 256, 256, 0, stream>>>(in, W[layer], hproj, N, K);
        attn_coef_kernel<<<(N * HEADS + 255) / 256, 256, 0, stream>>>(hproj, as_[layer], ad_[layer],
                                                                      asrc, adst, N);
        edge_logit_kernel<<<(Etot + 255) / 256, 256, 0, stream>>>(srcA, dstA, E, Etot, asrc, adst,
                                                                  elog, mu);
        edge_exp_kernel<<<(Etot + 255) / 256, 256, 0, stream>>>(srcA, dstA, E, Etot, mu, elog, ssum);
        int aggr_blocks = (int)(((long long)Etot * HD + 255) / 256);
        edge_aggr_kernel<<<aggr_blocks, 256, 0, stream>>>(srcA, dstA, E, Etot, elog, ssum, hproj, acc);
        bias_silu_kernel<<<(tot + 255) / 256, 256, 0, stream>>>(acc, bb[layer], hbuf, N);
    }

    hipMemsetAsync(pooled, 0, (size_t)NGRAPH * HD * 4, stream);
    pool_kernel<<<(N * HD + 255) / 256, 256, 0, stream>>>(hbuf, batch, pooled, N);
    head_kernel<<<1, 128, 0, stream>>>(pooled, Wr, br, (float*)d_out);
}

// Round 2
// 436.593 us; speedup vs baseline: 4.2950x; 4.2950x over previous
//
#include <hip/hip_runtime.h>
#include <cstdint>
#include <cstddef>

#define HEADS 4
#define HID 16
#define HD 64          // HEADS*HID
#define NCLS 10
#define NGRAPH 128
#define NEG_SLOPE 0.2f
#define SM_EPS 1e-16f

static inline size_t alignup(size_t x) { return (x + 255) & ~size_t(255); }

// ---------------- CSR build ----------------

__global__ void count_kernel(const int* __restrict__ dstA, int E, int Etot,
                             int* __restrict__ counts) {
    int e = blockIdx.x * blockDim.x + threadIdx.x;
    if (e >= Etot) return;
    int d = (e < E) ? dstA[e] : (e - E);
    atomicAdd(&counts[d], 1);
}

__global__ void scan1_kernel(const int* __restrict__ counts, int N, int* __restrict__ bsums) {
    __shared__ int sd[256];
    int tid = threadIdx.x;
    int i = blockIdx.x * 256 + tid;
    sd[tid] = (i < N) ? counts[i] : 0;
    __syncthreads();
    for (int s = 128; s > 0; s >>= 1) {
        if (tid < s) sd[tid] += sd[tid + s];
        __syncthreads();
    }
    if (tid == 0) bsums[blockIdx.x] = sd[0];
}

// exclusive scan of bsums in place (nb <= 256)
__global__ void scan2_kernel(int* __restrict__ bsums, int nb) {
    __shared__ int sd[256];
    int tid = threadIdx.x;
    int v = (tid < nb) ? bsums[tid] : 0;
    sd[tid] = v;
    __syncthreads();
    for (int off = 1; off < 256; off <<= 1) {
        int t = (tid >= off) ? sd[tid - off] : 0;
        __syncthreads();
        sd[tid] += t;
        __syncthreads();
    }
    if (tid < nb) bsums[tid] = sd[tid] - v;
}

__global__ void scan3_kernel(const int* __restrict__ counts, const int* __restrict__ bsums,
                             int N, int* __restrict__ row_ptr, int* __restrict__ cursor) {
    __shared__ int sd[256];
    int tid = threadIdx.x;
    int i = blockIdx.x * 256 + tid;
    int v = (i < N) ? counts[i] : 0;
    sd[tid] = v;
    __syncthreads();
    for (int off = 1; off < 256; off <<= 1) {
        int t = (tid >= off) ? sd[tid - off] : 0;
        __syncthreads();
        sd[tid] += t;
        __syncthreads();
    }
    int ex = sd[tid] - v + bsums[blockIdx.x];
    if (i < N) { row_ptr[i] = ex; cursor[i] = ex; }
}

__global__ void scatter_kernel(const int* __restrict__ srcA, const int* __restrict__ dstA,
                               int E, int Etot, int* __restrict__ cursor,
                               int* __restrict__ csr_src) {
    int e = blockIdx.x * blockDim.x + threadIdx.x;
    if (e >= Etot) return;
    int s = (e < E) ? srcA[e] : (e - E);
    int d = (e < E) ? dstA[e] : (e - E);
    int pos = atomicAdd(&cursor[d], 1);
    csr_src[pos] = s;
}

// ---------------- per-layer kernels ----------------

// h = in @ W (W staged in LDS), fused per-head attention coefficients.
// One wave handles 2 nodes; lane = output col.
template <int K>
__global__ void gemm_attn_kernel(const float* __restrict__ in, const float* __restrict__ W,
                                 const float* __restrict__ as_, const float* __restrict__ ad_,
                                 float* __restrict__ h, float* __restrict__ asrc,
                                 float* __restrict__ adst, int N) {
    __shared__ float Wl[K * HD];
    __shared__ float avl[HD], adl[HD];
    int tid = threadIdx.x;
    for (int i = tid; i < K * HD; i += 256) Wl[i] = W[i];
    if (tid < HD) { avl[tid] = as_[tid]; adl[tid] = ad_[tid]; }
    __syncthreads();

    int lane = tid & 63, wave = tid >> 6;
    int head = lane >> 4;
    int stride = gridDim.x * 4 * 2;
    for (int n0 = (blockIdx.x * 4 + wave) * 2; n0 < N; n0 += stride) {
        int n1 = n0 + 1;  // N is even, always valid
        const float4* x0 = (const float4*)(in + (size_t)n0 * K);
        const float4* x1 = (const float4*)(in + (size_t)n1 * K);
        float acc0 = 0.f, acc1 = 0.f;
#pragma unroll 8
        for (int k4 = 0; k4 < K / 4; k4++) {
            float4 a = x0[k4];
            float4 b = x1[k4];
            acc0 += a.x * Wl[(4 * k4 + 0) * HD + lane];
            acc1 += b.x * Wl[(4 * k4 + 0) * HD + lane];
            acc0 += a.y * Wl[(4 * k4 + 1) * HD + lane];
            acc1 += b.y * Wl[(4 * k4 + 1) * HD + lane];
            acc0 += a.z * Wl[(4 * k4 + 2) * HD + lane];
            acc1 += b.z * Wl[(4 * k4 + 2) * HD + lane];
            acc0 += a.w * Wl[(4 * k4 + 3) * HD + lane];
            acc1 += b.w * Wl[(4 * k4 + 3) * HD + lane];
        }
        h[(size_t)n0 * HD + lane] = acc0;
        h[(size_t)n1 * HD + lane] = acc1;
        float s0 = acc0 * avl[lane], d0 = acc0 * adl[lane];
        float s1 = acc1 * avl[lane], d1 = acc1 * adl[lane];
#pragma unroll
        for (int off = 1; off < 16; off <<= 1) {
            s0 += __shfl_xor(s0, off);
            d0 += __shfl_xor(d0, off);
            s1 += __shfl_xor(s1, off);
            d1 += __shfl_xor(d1, off);
        }
        if ((lane & 15) == 0) {
            asrc[n0 * HEADS + head] = s0;
            adst[n0 * HEADS + head] = d0;
            asrc[n1 * HEADS + head] = s1;
            adst[n1 * HEADS + head] = d1;
        }
    }
}

// One wave per destination node: online-softmax gather over in-edges.
// lane = output col (head = lane>>4). Fused bias + SiLU epilogue.
__global__ void gat_gather_kernel(const int* __restrict__ row_ptr, const int* __restrict__ csr_src,
                                  int N, int Etot, const float* __restrict__ h,
                                  const float* __restrict__ asrc, const float* __restrict__ adst,
                                  const float* __restrict__ bias, float* __restrict__ out) {
    int wid = (int)((blockIdx.x * (long long)blockDim.x + threadIdx.x) >> 6);
    if (wid >= N) return;
    int lane = threadIdx.x & 63;
    int head = lane >> 4;
    int beg = row_ptr[wid];
    int end = (wid + 1 < N) ? row_ptr[wid + 1] : Etot;
    float ad = adst[wid * HEADS + head];
    float m = -3.0e38f, ssum = 0.f, acc = 0.f;
#pragma unroll 2
    for (int p = beg; p < end; p++) {
        int s = csr_src[p];
        float l = asrc[s * HEADS + head] + ad;
        l = (l > 0.f) ? l : NEG_SLOPE * l;
        float hv = h[(size_t)s * HD + lane];
        float mn = fmaxf(m, l);
        float scale = __expf(m - mn);
        float w = __expf(l - mn);
        ssum = ssum * scale + w;
        acc = acc * scale + w * hv;
        m = mn;
    }
    float v = acc / (ssum + SM_EPS) + bias[lane];
    out[(size_t)wid * HD + lane] = v / (1.f + expf(-v));
}

// Run-length pooled sum: one wave per 64 consecutive (batch-sorted) nodes.
__global__ void pool_kernel(const float* __restrict__ h, const int* __restrict__ batch,
                            float* __restrict__ pooled, int N) {
    int gw = (int)((blockIdx.x * (long long)blockDim.x + threadIdx.x) >> 6);
    int lane = threadIdx.x & 63;
    int n_begin = gw * 64;
    if (n_begin >= N) return;
    int n_end = min(n_begin + 64, N);
    float acc = 0.f;
    int g = batch[n_begin];
    for (int n = n_begin; n < n_end; n++) {
        int gn = batch[n];
        if (gn != g) {
            atomicAdd(&pooled[(size_t)g * HD + lane], acc);
            acc = 0.f;
            g = gn;
        }
        acc += h[(size_t)n * HD + lane];
    }
    atomicAdd(&pooled[(size_t)g * HD + lane], acc);
}

__global__ void head_kernel(const float* __restrict__ pooled, const float* __restrict__ Wr,
                            const float* __restrict__ br, float* __restrict__ out) {
    int g = threadIdx.x;
    if (g >= NGRAPH) return;
    float l[NCLS];
    float mx = -1e30f;
#pragma unroll
    for (int c = 0; c < NCLS; c++) {
        float a = br[c];
        for (int k = 0; k < HD; k++) a += pooled[(size_t)g * HD + k] * Wr[k * NCLS + c];
        a = (a > 0.f) ? a : 0.f;
        l[c] = a;
        mx = fmaxf(mx, a);
    }
    float se = 0.f;
#pragma unroll
    for (int c = 0; c < NCLS; c++) se += expf(l[c] - mx);
    float lse = logf(se);
#pragma unroll
    for (int c = 0; c < NCLS; c++) out[(size_t)g * NCLS + c] = l[c] - mx - lse;
}

extern "C" void kernel_launch(void* const* d_in, const int* in_sizes, int n_in,
                              void* d_out, int out_size, void* d_ws, size_t ws_size,
                              hipStream_t stream) {
    const float* x = (const float*)d_in[0];
    const int* ei = (const int*)d_in[1];
    const int* batch = (const int*)d_in[2];
    const float* W[3]  = {(const float*)d_in[3], (const float*)d_in[7],  (const float*)d_in[11]};
    const float* bb[3] = {(const float*)d_in[4], (const float*)d_in[8],  (const float*)d_in[12]};
    const float* as_[3] = {(const float*)d_in[5], (const float*)d_in[9], (const float*)d_in[13]};
    const float* ad_[3] = {(const float*)d_in[6], (const float*)d_in[10], (const float*)d_in[14]};
    const float* Wr = (const float*)d_in[15];
    const float* br = (const float*)d_in[16];

    const int N = in_sizes[2];          // 50000
    const int E = in_sizes[1] / 2;      // 800000
    const int Etot = E + N;             // + self loops
    const int F0 = in_sizes[0] / N;     // 128

    char* p = (char*)d_ws;
    float* hproj = (float*)p; p += alignup((size_t)N * HD * 4);
    float* hbuf  = (float*)p; p += alignup((size_t)N * HD * 4);
    float* asrc  = (float*)p; p += alignup((size_t)N * HEADS * 4);
    float* adst  = (float*)p; p += alignup((size_t)N * HEADS * 4);
    int* counts  = (int*)p;   p += alignup((size_t)N * 4);
    int* row_ptr = (int*)p;   p += alignup((size_t)N * 4);
    int* cursor  = (int*)p;   p += alignup((size_t)N * 4);
    int* bsums   = (int*)p;   p += alignup(256 * 4);
    int* csr_src = (int*)p;   p += alignup((size_t)Etot * 4);
    float* pooled = (float*)p; p += alignup((size_t)NGRAPH * HD * 4);

    const int* srcA = ei;
    const int* dstA = ei + E;

    // ---- CSR build (once, reused by all 3 layers) ----
    hipMemsetAsync(counts, 0, (size_t)N * 4, stream);
    count_kernel<<<(Etot + 255) / 256, 256, 0, stream>>>(dstA, E, Etot, counts);
    int nb = (N + 255) / 256;
    scan1_kernel<<<nb, 256, 0, stream>>>(counts, N, bsums);
    scan2_kernel<<<1, 256, 0, stream>>>(bsums, nb);
    scan3_kernel<<<nb, 256, 0, stream>>>(counts, bsums, N, row_ptr, cursor);
    scatter_kernel<<<(Etot + 255) / 256, 256, 0, stream>>>(srcA, dstA, E, Etot, cursor, csr_src);

    // ---- layers ----
    int gather_blocks = (int)(((long long)N * 64 + 255) / 256);
    for (int layer = 0; layer < 3; layer++) {
        const float* in = (layer == 0) ? x : hbuf;
        if (layer == 0)
            gemm_attn_kernel<128><<<1024, 256, 0, stream>>>(in, W[layer], as_[layer], ad_[layer],
                                                            hproj, asrc, adst, N);
        else
            gemm_attn_kernel<64><<<1024, 256, 0, stream>>>(in, W[layer], as_[layer], ad_[layer],
                                                           hproj, asrc, adst, N);
        gat_gather_kernel<<<gather_blocks, 256, 0, stream>>>(row_ptr, csr_src, N, Etot, hproj,
                                                             asrc, adst, bb[layer], hbuf);
    }

    // ---- pooling + head ----
    hipMemsetAsync(pooled, 0, (size_t)NGRAPH * HD * 4, stream);
    int pool_waves = (N + 63) / 64;
    pool_kernel<<<(pool_waves * 64 + 255) / 256, 256, 0, stream>>>(hbuf, batch, pooled, N);
    head_kernel<<<1, 128, 0, stream>>>(pooled, Wr, br, (float*)d_out);
}